// Round 5
// baseline (167.744 us; speedup 1.0000x reference)
//
#include <hip/hip_runtime.h>

#define NNODES 50000
#define NEDGES 800000
#define HD 128            // HEADS*OUT_DIM
#define NEG 0.2f
#define MTILE 64
#define LDW 136           // bf16 row stride in LDS
#define MAXD 64           // per-node LDS edge cap in gat_node
#define GEMMB ((NNODES + MTILE - 1) / MTILE) // 782
#define NBINS 196         // ceil(NNODES/256) coarse bins (dst>>8)
#define CAP 5120          // per-bin capacity (mean 4082, +16 sigma)
#define GST 16            // gcnt line-padding stride
#define ABLK ((NEDGES + 2047) / 2048)        // 391 bucket blocks

typedef __attribute__((ext_vector_type(8))) short short8;
typedef __attribute__((ext_vector_type(4))) float floatx4;

static __device__ inline unsigned short f2bf(float f) {
    unsigned u = __float_as_uint(f);
    return (unsigned short)((u + 0x7FFF + ((u >> 16) & 1)) >> 16);
}
static __device__ inline float bf2f(unsigned short u) {
    return __uint_as_float(((unsigned)u) << 16);
}
static __device__ inline float lrelu_exp(float a) {
    a = (a > 0.f) ? a : NEG * a;
    return __expf(a);
}

// ---------------------------------------------------------------------------
// Kernel 1: blocks [0,GEMMB) = 64-row GEMM tile (bf16 MFMA, fused asrc/adst
// dots). Blocks [GEMMB,GEMMB+ABLK) = coarse bucketing: LDS-private 196-bin
// histogram over dst>>8, one global atomic per (block,bin), scatter packed
// (fine<<16|src) 4B entries into the bin window.
// ---------------------------------------------------------------------------
__global__ __launch_bounds__(256, 4) void gat_main(
    const float* __restrict__ x, const float* __restrict__ W,
    const float* __restrict__ att_src, const float* __restrict__ att_dst,
    const int* __restrict__ ei,
    unsigned short* __restrict__ h, float* __restrict__ asrc,
    float* __restrict__ adst, int* __restrict__ gcnt, int* __restrict__ cbuf)
{
    __shared__ unsigned short Wl[128 * LDW];          // 34816 B
    const int t = threadIdx.x;

    if (blockIdx.x >= GEMMB) {      // ---- coarse bucketing path ----
        int* hist = (int*)Wl;       // [256] reuse gemm LDS
        int* boff = hist + 256;     // [256]
        const int e0 = (blockIdx.x - GEMMB) * 2048 + t * 8;
        const bool act = (e0 < NEDGES);
        int4 s0 = make_int4(0, 0, 0, 0), s1 = s0, d0 = s0, d1 = s0;
        if (act) {
            s0 = *(const int4*)(ei + e0);
            s1 = *(const int4*)(ei + e0 + 4);
            d0 = *(const int4*)(ei + NEDGES + e0);
            d1 = *(const int4*)(ei + NEDGES + e0 + 4);
        }
        hist[t] = 0;
        __syncthreads();
        if (act) {
            atomicAdd(&hist[d0.x >> 8], 1); atomicAdd(&hist[d0.y >> 8], 1);
            atomicAdd(&hist[d0.z >> 8], 1); atomicAdd(&hist[d0.w >> 8], 1);
            atomicAdd(&hist[d1.x >> 8], 1); atomicAdd(&hist[d1.y >> 8], 1);
            atomicAdd(&hist[d1.z >> 8], 1); atomicAdd(&hist[d1.w >> 8], 1);
        }
        __syncthreads();
        if (t < NBINS && hist[t] > 0)
            boff[t] = atomicAdd(&gcnt[t * GST], hist[t]);
        __syncthreads();
        if (act) {
            int ss[8] = {s0.x, s0.y, s0.z, s0.w, s1.x, s1.y, s1.z, s1.w};
            int dd[8] = {d0.x, d0.y, d0.z, d0.w, d1.x, d1.y, d1.z, d1.w};
#pragma unroll
            for (int j = 0; j < 8; j++) {
                int b = dd[j] >> 8;
                int slot = atomicAdd(&boff[b], 1);      // LDS atomic
                cbuf[(size_t)b * CAP + slot] = ((dd[j] & 255) << 16) | ss[j];
            }
        }
        return;
    }

    // ---- GEMM path ----
    const int rowBase = blockIdx.x * MTILE;

    // W stage: fp32 -> bf16 into LDS
    for (int idx = t * 8; idx < 128 * 128; idx += 2048) {
        int r = idx >> 7, c = idx & 127;
        float4 v0 = *(const float4*)(W + idx);
        float4 v1 = *(const float4*)(W + idx + 4);
        short8 u;
        u[0] = (short)f2bf(v0.x); u[1] = (short)f2bf(v0.y);
        u[2] = (short)f2bf(v0.z); u[3] = (short)f2bf(v0.w);
        u[4] = (short)f2bf(v1.x); u[5] = (short)f2bf(v1.y);
        u[6] = (short)f2bf(v1.z); u[7] = (short)f2bf(v1.w);
        *(short8*)(Wl + r * LDW + c) = u;
    }

    // x A-fragments: global -> registers
    const int wave = t >> 6;
    const int lane = t & 63;
    const int c16  = lane & 15;
    const int quad = lane >> 4;
    const int xr   = rowBase + wave * 16 + c16;
    short8 av[4];
#pragma unroll
    for (int kc = 0; kc < 4; kc++) {
        float4 v0 = make_float4(0.f, 0.f, 0.f, 0.f);
        float4 v1 = v0;
        if (xr < NNODES) {
            const float* p = x + (size_t)xr * 128 + kc * 32 + quad * 8;
            v0 = *(const float4*)p;
            v1 = *(const float4*)(p + 4);
        }
        short8 u;
        u[0] = (short)f2bf(v0.x); u[1] = (short)f2bf(v0.y);
        u[2] = (short)f2bf(v0.z); u[3] = (short)f2bf(v0.w);
        u[4] = (short)f2bf(v1.x); u[5] = (short)f2bf(v1.y);
        u[6] = (short)f2bf(v1.z); u[7] = (short)f2bf(v1.w);
        av[kc] = u;
    }
    __syncthreads();

    floatx4 acc[8];
#pragma unroll
    for (int nt = 0; nt < 8; nt++) acc[nt] = (floatx4)(0.f);

#pragma unroll
    for (int kc = 0; kc < 4; kc++) {
#pragma unroll
        for (int nt = 0; nt < 8; nt++) {
            short8 bv = *(const short8*)(Wl + (nt * 16 + c16) * LDW + kc * 32 + quad * 8);
            acc[nt] = __builtin_amdgcn_mfma_f32_16x16x32_bf16(av[kc], bv, acc[nt], 0, 0, 0);
        }
    }

    float As[8], Ad[8];
#pragma unroll
    for (int nt = 0; nt < 8; nt++) {
        As[nt] = att_src[nt * 16 + c16];
        Ad[nt] = att_dst[nt * 16 + c16];
    }
#pragma unroll
    for (int r = 0; r < 4; r++) {
        const int gr = rowBase + wave * 16 + quad * 4 + r;
#pragma unroll
        for (int hh = 0; hh < 4; hh++) {
            float ps = acc[2 * hh][r] * As[2 * hh] + acc[2 * hh + 1][r] * As[2 * hh + 1];
            float pd = acc[2 * hh][r] * Ad[2 * hh] + acc[2 * hh + 1][r] * Ad[2 * hh + 1];
#pragma unroll
            for (int m = 8; m >= 1; m >>= 1) {
                ps += __shfl_xor(ps, m, 64);
                pd += __shfl_xor(pd, m, 64);
            }
            if (c16 == 0 && gr < NNODES) {
                asrc[gr * 4 + hh] = ps;
                adst[gr * 4 + hh] = pd;
            }
        }
    }

    // epilogue: C bounce through Wl for 16B coalesced h stores
    __syncthreads();
#pragma unroll
    for (int r = 0; r < 4; r++) {
        const int lr = wave * 16 + quad * 4 + r;
#pragma unroll
        for (int nt = 0; nt < 8; nt++)
            Wl[lr * LDW + nt * 16 + c16] = f2bf(acc[nt][r]);
    }
    __syncthreads();
    for (int idx = t * 8; idx < MTILE * 128; idx += 2048) {
        int r = idx >> 7, c = idx & 127;
        int g = rowBase + r;
        if (g < NNODES)
            *(short8*)(h + (size_t)g * HD + c) = *(const short8*)(Wl + r * LDW + c);
    }
}

// ---------------------------------------------------------------------------
// Kernel 2: per coarse bin (256 nodes): fine 256-bin LDS histogram + scan ->
// coff[]; scatter srcs grouped-by-node into LDS, then COALESCED dump to a
// 2B/edge ushort CSR. Zero global atomics, zero scattered global writes.
// ---------------------------------------------------------------------------
__global__ __launch_bounds__(1024) void gat_bin(
    const int* __restrict__ gcnt, const int* __restrict__ cbuf,
    int* __restrict__ coff, unsigned short* __restrict__ csr)
{
    __shared__ unsigned short eb[CAP];      // 10240 B
    __shared__ int sh[256], hist[256], run[256];
    const int t = threadIdx.x;
    const int b = blockIdx.x;
    const int c_b = gcnt[b * GST];
    const size_t wbase = (size_t)b * CAP;

    if (t < 256) {
        sh[t] = (t < NBINS) ? gcnt[t * GST] : 0;
        hist[t] = 0;
    }
    __syncthreads();
    for (int off = 1; off < 256; off <<= 1) {
        int u = (t < 256 && t >= off) ? sh[t - off] : 0;
        __syncthreads();
        if (t < 256) sh[t] += u;
        __syncthreads();
    }
    const int binbase = sh[b] - c_b;

    // fine histogram over dst&255
    for (int i = t; i < c_b; i += 1024)
        atomicAdd(&hist[(cbuf[wbase + i] >> 16) & 255], 1);
    __syncthreads();

    // scan fine hist -> exclusive offsets; emit coff; run = running offsets
    int hv = 0;
    if (t < 256) { hv = hist[t]; sh[t] = hv; }
    __syncthreads();
    for (int off = 1; off < 256; off <<= 1) {
        int u = (t < 256 && t >= off) ? sh[t - off] : 0;
        __syncthreads();
        if (t < 256) sh[t] += u;
        __syncthreads();
    }
    if (t < 256) {
        int ex = sh[t] - hv;
        int n = b * 256 + t;
        if (n < NNODES) coff[n] = binbase + ex;
        run[t] = ex;
    }
    if (b == 0 && t == 0) coff[NNODES] = NEDGES;
    __syncthreads();

    // scatter grouped-by-node into LDS
    for (int i = t; i < c_b; i += 1024) {
        int e = cbuf[wbase + i];
        int slot = atomicAdd(&run[(e >> 16) & 255], 1);     // LDS atomic
        eb[slot] = (unsigned short)(e & 0xFFFF);
    }
    __syncthreads();

    // coalesced dump
    for (int i = t; i < c_b; i += 1024)
        csr[binbase + i] = eb[i];
}

// ---------------------------------------------------------------------------
// Kernel 3: per-node aggregation, 6250 blocks, 8 nodes/block, 32 lanes/node.
// Phase 1: gather asrc[src] (L2-resident), exp weights -> LDS stash + per-head
// sums -> rsumr. Phase 2: TWO edges per group concurrently — 16 lanes x
// ushort8 (16B) cover one 256B h-row; 4-pair unroll = 8 edges / 4 loads in
// flight per lane. Halves combined by one shfl_xor(16).
// ---------------------------------------------------------------------------
__global__ __launch_bounds__(256) void gat_node(
    const int* __restrict__ coff, const unsigned short* __restrict__ csr,
    const float* __restrict__ asrc, const float* __restrict__ adst,
    const unsigned short* __restrict__ h, const float* __restrict__ bias,
    float* __restrict__ out, float* __restrict__ rsumr)
{
    __shared__ unsigned short sh_src[8 * MAXD];
    __shared__ float sh_w[8 * MAXD * 4];
    const int t = threadIdx.x;
    const int node8 = t >> 5;
    const int n = blockIdx.x * 8 + node8;
    const int k = t & 31;
    const int beg = coff[n], end = coff[n + 1];
    const int base = node8 * MAXD;
    const float4 bn = *(const float4*)(adst + n * 4);

    // phase 1: weights + sums + stash (lanes of a group stay in one wave-half
    // -> stash writes/reads are wave-synchronous)
    float4 sum = make_float4(0.f, 0.f, 0.f, 0.f);
    for (int j = beg + k; j < end; j += 32) {
        int s = csr[j];
        float4 a = *(const float4*)(asrc + s * 4);
        float4 wv;
        wv.x = lrelu_exp(a.x + bn.x);
        wv.y = lrelu_exp(a.y + bn.y);
        wv.z = lrelu_exp(a.z + bn.z);
        wv.w = lrelu_exp(a.w + bn.w);
        sum.x += wv.x; sum.y += wv.y; sum.z += wv.z; sum.w += wv.w;
        int i = j - beg;
        if (i < MAXD) {
            sh_src[base + i] = (unsigned short)s;
            *(float4*)(sh_w + (base + i) * 4) = wv;
        }
    }
#pragma unroll
    for (int m = 16; m >= 1; m >>= 1) {
        sum.x += __shfl_xor(sum.x, m, 64);
        sum.y += __shfl_xor(sum.y, m, 64);
        sum.z += __shfl_xor(sum.z, m, 64);
        sum.w += __shfl_xor(sum.w, m, 64);
    }
    float rs[4];
    rs[0] = 1.f / (sum.x + 1e-16f);
    rs[1] = 1.f / (sum.y + 1e-16f);
    rs[2] = 1.f / (sum.z + 1e-16f);
    rs[3] = 1.f / (sum.w + 1e-16f);
    if (k == 0)
        *(float4*)(rsumr + n * 4) = make_float4(rs[0], rs[1], rs[2], rs[3]);

    // phase 2: 2-edge / ushort8 gather
    const int half = k >> 4;          // which edge of the pair
    const int i16  = k & 15;          // 8-elem chunk of the row
    const int head = i16 >> 2;
    const float rsel = rs[head];
    const int lim = (end - beg < MAXD) ? end - beg : MAXD;

    float accA[8], accB[8];
#pragma unroll
    for (int m = 0; m < 8; m++) { accA[m] = 0.f; accB[m] = 0.f; }

    int j = 0;
    for (; j + 8 <= lim; j += 8) {
        int e0 = j + half, e1 = j + 2 + half, e2 = j + 4 + half, e3 = j + 6 + half;
        int s0 = sh_src[base + e0];
        int s1 = sh_src[base + e1];
        int s2 = sh_src[base + e2];
        int s3 = sh_src[base + e3];
        float w0 = sh_w[(base + e0) * 4 + head] * rsel;
        float w1 = sh_w[(base + e1) * 4 + head] * rsel;
        float w2 = sh_w[(base + e2) * 4 + head] * rsel;
        float w3 = sh_w[(base + e3) * 4 + head] * rsel;
        short8 u0 = *(const short8*)(h + (size_t)s0 * HD + i16 * 8);
        short8 u1 = *(const short8*)(h + (size_t)s1 * HD + i16 * 8);
        short8 u2 = *(const short8*)(h + (size_t)s2 * HD + i16 * 8);
        short8 u3 = *(const short8*)(h + (size_t)s3 * HD + i16 * 8);
#pragma unroll
        for (int m = 0; m < 8; m++) {
            accA[m] = fmaf(bf2f((unsigned short)u0[m]), w0, accA[m]);
            accB[m] = fmaf(bf2f((unsigned short)u1[m]), w1, accB[m]);
            accA[m] = fmaf(bf2f((unsigned short)u2[m]), w2, accA[m]);
            accB[m] = fmaf(bf2f((unsigned short)u3[m]), w3, accB[m]);
        }
    }
    for (; j + 2 <= lim; j += 2) {
        int e0 = j + half;
        int s0 = sh_src[base + e0];
        float w0 = sh_w[(base + e0) * 4 + head] * rsel;
        short8 u0 = *(const short8*)(h + (size_t)s0 * HD + i16 * 8);
#pragma unroll
        for (int m = 0; m < 8; m++)
            accA[m] = fmaf(bf2f((unsigned short)u0[m]), w0, accA[m]);
    }
    if (j < lim && half == 0) {       // odd tail edge: half 0 only
        int s0 = sh_src[base + j];
        float w0 = sh_w[(base + j) * 4 + head] * rsel;
        short8 u0 = *(const short8*)(h + (size_t)s0 * HD + i16 * 8);
#pragma unroll
        for (int m = 0; m < 8; m++)
            accA[m] = fmaf(bf2f((unsigned short)u0[m]), w0, accA[m]);
    }
    // rare overflow fallback: recompute weight from asrc (scalar per head)
    const float bnh = ((const float*)&bn)[head];
    for (int jj = beg + MAXD + half; jj < end; jj += 2) {
        int s0 = csr[jj];
        float w0 = lrelu_exp(asrc[s0 * 4 + head] + bnh) * rsel;
        short8 u0 = *(const short8*)(h + (size_t)s0 * HD + i16 * 8);
#pragma unroll
        for (int m = 0; m < 8; m++)
            accA[m] = fmaf(bf2f((unsigned short)u0[m]), w0, accA[m]);
    }

#pragma unroll
    for (int m = 0; m < 8; m++) {
        accA[m] += accB[m];
        accA[m] += __shfl_xor(accA[m], 16, 64);   // combine the two halves
    }
    // lane half==0 stores elems [i16*8, +4), half==1 stores [i16*8+4, +8)
    const float4 b4 = *(const float4*)(bias + i16 * 8 + half * 4);
    float4 st;
    st.x = accA[half * 4 + 0] + b4.x;
    st.y = accA[half * 4 + 1] + b4.y;
    st.z = accA[half * 4 + 2] + b4.z;
    st.w = accA[half * 4 + 3] + b4.w;
    *(float4*)(out + (size_t)n * HD + i16 * 8 + half * 4) = st;
}

// ---------------------------------------------------------------------------
// Kernel 4: alpha_pooled, edge order, fully coalesced; gathers from
// asrc/adst/rsumr (2.4 MB total, L2-resident).
// ---------------------------------------------------------------------------
static __device__ inline float apool1(
    int s, int d, const float* __restrict__ asrc,
    const float* __restrict__ adst, const float* __restrict__ rsumr)
{
    float4 a = *(const float4*)(asrc + s * 4);
    float4 b = *(const float4*)(adst + d * 4);
    float4 r = *(const float4*)(rsumr + d * 4);
    return 0.25f * (lrelu_exp(a.x + b.x) * r.x + lrelu_exp(a.y + b.y) * r.y +
                    lrelu_exp(a.z + b.z) * r.z + lrelu_exp(a.w + b.w) * r.w);
}

__global__ __launch_bounds__(256) void gat_apool(
    const int* __restrict__ ei, const float* __restrict__ asrc,
    const float* __restrict__ adst, const float* __restrict__ rsumr,
    float* __restrict__ apool)
{
    int e0 = (blockIdx.x * 256 + threadIdx.x) * 4;
    if (e0 >= NEDGES) return;
    int4 s = *(const int4*)(ei + e0);
    int4 d = *(const int4*)(ei + NEDGES + e0);
    float4 r;
    r.x = apool1(s.x, d.x, asrc, adst, rsumr);
    r.y = apool1(s.y, d.y, asrc, adst, rsumr);
    r.z = apool1(s.z, d.z, asrc, adst, rsumr);
    r.w = apool1(s.w, d.w, asrc, adst, rsumr);
    *(float4*)(apool + e0) = r;
}

// ---------------------------------------------------------------------------
extern "C" void kernel_launch(void* const* d_in, const int* in_sizes, int n_in,
                              void* d_out, int out_size, void* d_ws, size_t ws_size,
                              hipStream_t stream)
{
    const float* x       = (const float*)d_in[0];
    const int*   ei      = (const int*)d_in[1];
    const float* W       = (const float*)d_in[2];
    const float* att_src = (const float*)d_in[3];
    const float* att_dst = (const float*)d_in[4];
    const float* bias    = (const float*)d_in[5];

    float* out   = (float*)d_out;                    // (N,128)
    float* apool = out + (size_t)NNODES * HD;        // (E,)

    // workspace layout
    unsigned short* h = (unsigned short*)d_ws;            // N*128 bf16
    float* asrc  = (float*)(h + (size_t)NNODES * HD);     // N*4
    float* adst  = asrc + NNODES * 4;                     // N*4
    float* rsumr = adst + NNODES * 4;                     // N*4
    int*   gcnt  = (int*)(rsumr + NNODES * 4);            // NBINS*GST
    int*   coff  = gcnt + NBINS * GST;                    // N+1 (+pad)
    int*   cbuf  = coff + NNODES + 4;                     // NBINS*CAP ints
    unsigned short* csr = (unsigned short*)(cbuf + (size_t)NBINS * CAP); // E

    hipMemsetAsync(gcnt, 0, (size_t)NBINS * GST * sizeof(int), stream);

    gat_main<<<GEMMB + ABLK, 256, 0, stream>>>(
        x, W, att_src, att_dst, ei, h, asrc, adst, gcnt, cbuf);
    gat_bin<<<NBINS, 1024, 0, stream>>>(gcnt, cbuf, coff, csr);
    gat_node<<<NNODES / 8, 256, 0, stream>>>(
        coff, csr, asrc, adst, h, bias, out, rsumr);
    gat_apool<<<(NEDGES / 4 + 255) / 256, 256, 0, stream>>>(
        ei, asrc, adst, rsumr, apool);
}

// Round 6
// 160.066 us; speedup vs baseline: 1.0480x; 1.0480x over previous
//
#include <hip/hip_runtime.h>

#define NNODES 50000
#define NEDGES 800000
#define HD 128            // HEADS*OUT_DIM
#define NEG 0.2f
#define MTILE 64
#define LDW 136           // bf16 row stride in LDS
#define MAXD 64           // per-node LDS edge cap in gat_node
#define GEMMB ((NNODES + MTILE - 1) / MTILE) // 782
#define NBINS 196         // ceil(NNODES/256) coarse bins (dst>>8)
#define CAP 5120          // per-bin capacity (mean 4082, +16 sigma)
#define ABLK ((NEDGES + 2047) / 2048)        // 391 bucket blocks

typedef __attribute__((ext_vector_type(8))) short short8;
typedef __attribute__((ext_vector_type(4))) float floatx4;

static __device__ inline unsigned short f2bf(float f) {
    unsigned u = __float_as_uint(f);
    return (unsigned short)((u + 0x7FFF + ((u >> 16) & 1)) >> 16);
}
static __device__ inline float bf2f(unsigned short u) {
    return __uint_as_float(((unsigned)u) << 16);
}
static __device__ inline float lrelu_exp(float a) {
    a = (a > 0.f) ? a : NEG * a;
    return __expf(a);
}

// ---------------------------------------------------------------------------
// Kernel 1: blocks [0,GEMMB) = 64-row GEMM tile (bf16 MFMA, fused asrc/adst
// dots). Blocks [GEMMB,GEMMB+ABLK) = per-block LDS counting sort of 2048
// edges by coarse bin (dst>>8): hist -> scan -> LDS scatter -> COALESCED dump
// to sbuf + per-block offset table Sg. ZERO global atomics (the former
// 391-deep same-line reservation chains were the ~50us wall).
// ---------------------------------------------------------------------------
__global__ __launch_bounds__(256, 4) void gat_main(
    const float* __restrict__ x, const float* __restrict__ W,
    const float* __restrict__ att_src, const float* __restrict__ att_dst,
    const int* __restrict__ ei,
    unsigned short* __restrict__ h, float* __restrict__ asrc,
    float* __restrict__ adst, int* __restrict__ Sg, int* __restrict__ sbuf)
{
    __shared__ __align__(16) unsigned short Wl[128 * LDW];    // 34816 B
    const int t = threadIdx.x;

    if (blockIdx.x >= GEMMB) {      // ---- bucket path (local sort) ----
        int* hist = (int*)Wl;       // [256]
        int* sh   = hist + 256;     // [256]
        int* run  = sh + 256;       // [256]
        int* lbuf = run + 256;      // [2048] packed (fine<<16|src)
        const int blk = blockIdx.x - GEMMB;
        const int e0 = blk * 2048 + t * 8;
        const bool act = (e0 < NEDGES);
        const int cnt = (blk == ABLK - 1) ? (NEDGES - blk * 2048) : 2048;
        int4 s0 = make_int4(0, 0, 0, 0), s1 = s0, d0 = s0, d1 = s0;
        if (act) {
            s0 = *(const int4*)(ei + e0);
            s1 = *(const int4*)(ei + e0 + 4);
            d0 = *(const int4*)(ei + NEDGES + e0);
            d1 = *(const int4*)(ei + NEDGES + e0 + 4);
        }
        hist[t] = 0;
        __syncthreads();
        if (act) {
            atomicAdd(&hist[d0.x >> 8], 1); atomicAdd(&hist[d0.y >> 8], 1);
            atomicAdd(&hist[d0.z >> 8], 1); atomicAdd(&hist[d0.w >> 8], 1);
            atomicAdd(&hist[d1.x >> 8], 1); atomicAdd(&hist[d1.y >> 8], 1);
            atomicAdd(&hist[d1.z >> 8], 1); atomicAdd(&hist[d1.w >> 8], 1);
        }
        __syncthreads();
        int hv = hist[t];
        sh[t] = hv;
        __syncthreads();
        for (int off = 1; off < 256; off <<= 1) {
            int u = (t >= off) ? sh[t - off] : 0;
            __syncthreads();
            sh[t] += u;
            __syncthreads();
        }
        int ex = sh[t] - hv;
        run[t] = ex;
        Sg[blk * 257 + t] = ex;                    // coalesced offset table
        if (t == 0) Sg[blk * 257 + 256] = cnt;
        __syncthreads();
        if (act) {
            int ss[8] = {s0.x, s0.y, s0.z, s0.w, s1.x, s1.y, s1.z, s1.w};
            int dd[8] = {d0.x, d0.y, d0.z, d0.w, d1.x, d1.y, d1.z, d1.w};
#pragma unroll
            for (int j = 0; j < 8; j++) {
                int slot = atomicAdd(&run[dd[j] >> 8], 1);  // LDS atomic
                lbuf[slot] = ((dd[j] & 255) << 16) | ss[j];
            }
        }
        __syncthreads();
        for (int i = t; i < cnt; i += 256)          // coalesced dump
            sbuf[blk * 2048 + i] = lbuf[i];
        return;
    }

    // ---- GEMM path ----
    const int rowBase = blockIdx.x * MTILE;

    // W stage: fp32 -> bf16 into LDS
    for (int idx = t * 8; idx < 128 * 128; idx += 2048) {
        int r = idx >> 7, c = idx & 127;
        float4 v0 = *(const float4*)(W + idx);
        float4 v1 = *(const float4*)(W + idx + 4);
        short8 u;
        u[0] = (short)f2bf(v0.x); u[1] = (short)f2bf(v0.y);
        u[2] = (short)f2bf(v0.z); u[3] = (short)f2bf(v0.w);
        u[4] = (short)f2bf(v1.x); u[5] = (short)f2bf(v1.y);
        u[6] = (short)f2bf(v1.z); u[7] = (short)f2bf(v1.w);
        *(short8*)(Wl + r * LDW + c) = u;
    }

    // x A-fragments: global -> registers
    const int wave = t >> 6;
    const int lane = t & 63;
    const int c16  = lane & 15;
    const int quad = lane >> 4;
    const int xr   = rowBase + wave * 16 + c16;
    short8 av[4];
#pragma unroll
    for (int kc = 0; kc < 4; kc++) {
        float4 v0 = make_float4(0.f, 0.f, 0.f, 0.f);
        float4 v1 = v0;
        if (xr < NNODES) {
            const float* p = x + (size_t)xr * 128 + kc * 32 + quad * 8;
            v0 = *(const float4*)p;
            v1 = *(const float4*)(p + 4);
        }
        short8 u;
        u[0] = (short)f2bf(v0.x); u[1] = (short)f2bf(v0.y);
        u[2] = (short)f2bf(v0.z); u[3] = (short)f2bf(v0.w);
        u[4] = (short)f2bf(v1.x); u[5] = (short)f2bf(v1.y);
        u[6] = (short)f2bf(v1.z); u[7] = (short)f2bf(v1.w);
        av[kc] = u;
    }
    __syncthreads();

    floatx4 acc[8];
#pragma unroll
    for (int nt = 0; nt < 8; nt++) acc[nt] = (floatx4)(0.f);

#pragma unroll
    for (int kc = 0; kc < 4; kc++) {
#pragma unroll
        for (int nt = 0; nt < 8; nt++) {
            short8 bv = *(const short8*)(Wl + (nt * 16 + c16) * LDW + kc * 32 + quad * 8);
            acc[nt] = __builtin_amdgcn_mfma_f32_16x16x32_bf16(av[kc], bv, acc[nt], 0, 0, 0);
        }
    }

    float As[8], Ad[8];
#pragma unroll
    for (int nt = 0; nt < 8; nt++) {
        As[nt] = att_src[nt * 16 + c16];
        Ad[nt] = att_dst[nt * 16 + c16];
    }
#pragma unroll
    for (int r = 0; r < 4; r++) {
        const int gr = rowBase + wave * 16 + quad * 4 + r;
#pragma unroll
        for (int hh = 0; hh < 4; hh++) {
            float ps = acc[2 * hh][r] * As[2 * hh] + acc[2 * hh + 1][r] * As[2 * hh + 1];
            float pd = acc[2 * hh][r] * Ad[2 * hh] + acc[2 * hh + 1][r] * Ad[2 * hh + 1];
#pragma unroll
            for (int m = 8; m >= 1; m >>= 1) {
                ps += __shfl_xor(ps, m, 64);
                pd += __shfl_xor(pd, m, 64);
            }
            if (c16 == 0 && gr < NNODES) {
                asrc[gr * 4 + hh] = ps;
                adst[gr * 4 + hh] = pd;
            }
        }
    }

    // epilogue: C bounce through Wl for 16B coalesced h stores
    __syncthreads();
#pragma unroll
    for (int r = 0; r < 4; r++) {
        const int lr = wave * 16 + quad * 4 + r;
#pragma unroll
        for (int nt = 0; nt < 8; nt++)
            Wl[lr * LDW + nt * 16 + c16] = f2bf(acc[nt][r]);
    }
    __syncthreads();
    for (int idx = t * 8; idx < MTILE * 128; idx += 2048) {
        int r = idx >> 7, c = idx & 127;
        int g = rowBase + r;
        if (g < NNODES)
            *(short8*)(h + (size_t)g * HD + c) = *(const short8*)(Wl + r * LDW + c);
    }
}

// ---------------------------------------------------------------------------
// Kernel 2: per coarse bin: gather the 391 per-block segments (via Sg) into
// LDS, fine 256-bin hist + scan -> coffB/coffE, LDS scatter grouped by node,
// coalesced dump to ushort CSR at per-bin base b*CAP. Zero global atomics.
// ---------------------------------------------------------------------------
__global__ __launch_bounds__(1024) void gat_bin(
    const int* __restrict__ Sg, const int* __restrict__ sbuf,
    int* __restrict__ coffB, int* __restrict__ coffE,
    unsigned short* __restrict__ csr)
{
    __shared__ int s0arr[391];
    __shared__ int segoff[391];
    __shared__ int ebi[CAP];
    __shared__ unsigned short ebs[CAP];
    __shared__ int hist[256], run[256], sh[512];
    const int t = threadIdx.x;
    const int b = blockIdx.x;

    int s0v = 0, lenv = 0;
    if (t < 391) {
        s0v = Sg[t * 257 + b];
        lenv = Sg[t * 257 + b + 1] - s0v;
        s0arr[t] = s0v;
    }
    if (t < 256) hist[t] = 0;
    // scan seglen over 512 slots -> exclusive segoff, total c_b
    if (t < 512) sh[t] = (t < 391) ? lenv : 0;
    __syncthreads();
    for (int off = 1; off < 512; off <<= 1) {
        int u = (t < 512 && t >= off) ? sh[t - off] : 0;
        __syncthreads();
        if (t < 512) sh[t] += u;
        __syncthreads();
    }
    if (t < 391) segoff[t] = sh[t] - lenv;
    __syncthreads();
    const int c_b = sh[390];

    // gather: binary search containing segment per edge slot
    for (int i = t; i < c_b; i += 1024) {
        int lo = 0, hi = 390;
        while (lo < hi) {
            int mid = (lo + hi + 1) >> 1;
            if (segoff[mid] <= i) lo = mid; else hi = mid - 1;
        }
        int e = sbuf[lo * 2048 + s0arr[lo] + (i - segoff[lo])];
        ebi[i] = e;
        atomicAdd(&hist[(e >> 16) & 255], 1);      // LDS atomic
    }
    __syncthreads();

    // scan fine hist -> coffB/coffE + running offsets
    int hv = (t < 256) ? hist[t] : 0;
    if (t < 256) sh[t] = hv;
    __syncthreads();
    for (int off = 1; off < 256; off <<= 1) {
        int u = (t < 256 && t >= off) ? sh[t - off] : 0;
        __syncthreads();
        if (t < 256) sh[t] += u;
        __syncthreads();
    }
    if (t < 256) {
        int ex = sh[t] - hv;
        run[t] = ex;
        int n = b * 256 + t;
        if (n < NNODES) {
            coffB[n] = b * CAP + ex;
            coffE[n] = b * CAP + ex + hv;
        }
    }
    __syncthreads();

    // scatter grouped-by-node into LDS
    for (int i = t; i < c_b; i += 1024) {
        int e = ebi[i];
        int slot = atomicAdd(&run[(e >> 16) & 255], 1);     // LDS atomic
        ebs[slot] = (unsigned short)(e & 0xFFFF);
    }
    __syncthreads();

    // coalesced dump
    for (int i = t; i < c_b; i += 1024)
        csr[(size_t)b * CAP + i] = ebs[i];
}

// ---------------------------------------------------------------------------
// Kernel 3: per-node aggregation, 12500 blocks, 4 nodes/block, 64 lanes/node
// (one full wave per node). Phase 1: exp weights -> LDS stash + per-head sums
// -> rsumr. Phase 2: FOUR edges concurrently (one per 16-lane quad), 16 lanes
// x ushort8 cover one 256B h-row; 4-step unroll = 16 edges in flight/wave.
// Quads combined by shfl_xor(16)+shfl_xor(32); quads 0/1 store the row.
// ---------------------------------------------------------------------------
__global__ __launch_bounds__(256) void gat_node(
    const int* __restrict__ coffB, const int* __restrict__ coffE,
    const unsigned short* __restrict__ csr,
    const float* __restrict__ asrc, const float* __restrict__ adst,
    const unsigned short* __restrict__ h, const float* __restrict__ bias,
    float* __restrict__ out, float* __restrict__ rsumr)
{
    __shared__ unsigned short sh_src[4 * MAXD];
    __shared__ float sh_w[4 * MAXD * 4];
    const int t = threadIdx.x;
    const int w = t >> 6;                  // node slot (== wave id)
    const int lane = t & 63;
    const int n = blockIdx.x * 4 + w;      // 12500*4 == NNODES exactly
    const int beg = coffB[n], end = coffE[n];
    const int base = w * MAXD;
    const float4 bn = *(const float4*)(adst + n * 4);

    // phase 1: weights + sums + stash (single wave -> no barrier needed)
    float4 sum = make_float4(0.f, 0.f, 0.f, 0.f);
    for (int j = beg + lane; j < end; j += 64) {
        int s = csr[j];
        float4 a = *(const float4*)(asrc + s * 4);
        float4 wv;
        wv.x = lrelu_exp(a.x + bn.x);
        wv.y = lrelu_exp(a.y + bn.y);
        wv.z = lrelu_exp(a.z + bn.z);
        wv.w = lrelu_exp(a.w + bn.w);
        sum.x += wv.x; sum.y += wv.y; sum.z += wv.z; sum.w += wv.w;
        int i = j - beg;
        if (i < MAXD) {
            sh_src[base + i] = (unsigned short)s;
            *(float4*)(sh_w + (base + i) * 4) = wv;
        }
    }
#pragma unroll
    for (int m = 32; m >= 1; m >>= 1) {
        sum.x += __shfl_xor(sum.x, m, 64);
        sum.y += __shfl_xor(sum.y, m, 64);
        sum.z += __shfl_xor(sum.z, m, 64);
        sum.w += __shfl_xor(sum.w, m, 64);
    }
    float rs[4];
    rs[0] = 1.f / (sum.x + 1e-16f);
    rs[1] = 1.f / (sum.y + 1e-16f);
    rs[2] = 1.f / (sum.z + 1e-16f);
    rs[3] = 1.f / (sum.w + 1e-16f);
    if (lane == 0)
        *(float4*)(rsumr + n * 4) = make_float4(rs[0], rs[1], rs[2], rs[3]);

    // phase 2: 4-edge / ushort8 gather
    const int quad = lane >> 4;       // which edge of the quartet
    const int i16  = lane & 15;       // 8-elem chunk of the row
    const int head = i16 >> 2;
    const float rsel = rs[head];
    const int lim = (end - beg < MAXD) ? end - beg : MAXD;

    float accA[8], accB[8];
#pragma unroll
    for (int m = 0; m < 8; m++) { accA[m] = 0.f; accB[m] = 0.f; }

    int j = 0;
    for (; j + 16 <= lim; j += 16) {
        int e0 = j + quad, e1 = j + 4 + quad, e2 = j + 8 + quad, e3 = j + 12 + quad;
        int s0 = sh_src[base + e0];
        int s1 = sh_src[base + e1];
        int s2 = sh_src[base + e2];
        int s3 = sh_src[base + e3];
        float w0 = sh_w[(base + e0) * 4 + head] * rsel;
        float w1 = sh_w[(base + e1) * 4 + head] * rsel;
        float w2 = sh_w[(base + e2) * 4 + head] * rsel;
        float w3 = sh_w[(base + e3) * 4 + head] * rsel;
        short8 u0 = *(const short8*)(h + (size_t)s0 * HD + i16 * 8);
        short8 u1 = *(const short8*)(h + (size_t)s1 * HD + i16 * 8);
        short8 u2 = *(const short8*)(h + (size_t)s2 * HD + i16 * 8);
        short8 u3 = *(const short8*)(h + (size_t)s3 * HD + i16 * 8);
#pragma unroll
        for (int m = 0; m < 8; m++) {
            accA[m] = fmaf(bf2f((unsigned short)u0[m]), w0, accA[m]);
            accB[m] = fmaf(bf2f((unsigned short)u1[m]), w1, accB[m]);
            accA[m] = fmaf(bf2f((unsigned short)u2[m]), w2, accA[m]);
            accB[m] = fmaf(bf2f((unsigned short)u3[m]), w3, accB[m]);
        }
    }
    for (; j + 4 <= lim; j += 4) {
        int e0 = j + quad;
        int s0 = sh_src[base + e0];
        float w0 = sh_w[(base + e0) * 4 + head] * rsel;
        short8 u0 = *(const short8*)(h + (size_t)s0 * HD + i16 * 8);
#pragma unroll
        for (int m = 0; m < 8; m++)
            accA[m] = fmaf(bf2f((unsigned short)u0[m]), w0, accA[m]);
    }
    if (quad < lim - j) {             // tail (rem in {1,2,3})
        int s0 = sh_src[base + j + quad];
        float w0 = sh_w[(base + j + quad) * 4 + head] * rsel;
        short8 u0 = *(const short8*)(h + (size_t)s0 * HD + i16 * 8);
#pragma unroll
        for (int m = 0; m < 8; m++)
            accA[m] = fmaf(bf2f((unsigned short)u0[m]), w0, accA[m]);
    }
    // rare overflow fallback: recompute weight from asrc (per-head scalar)
    const float bnh = (head == 0) ? bn.x : (head == 1) ? bn.y
                     : (head == 2) ? bn.z : bn.w;
    for (int jj = beg + MAXD + quad; jj < end; jj += 4) {
        int s0 = csr[jj];
        float w0 = lrelu_exp(asrc[s0 * 4 + head] + bnh) * rsel;
        short8 u0 = *(const short8*)(h + (size_t)s0 * HD + i16 * 8);
#pragma unroll
        for (int m = 0; m < 8; m++)
            accA[m] = fmaf(bf2f((unsigned short)u0[m]), w0, accA[m]);
    }

#pragma unroll
    for (int m = 0; m < 8; m++) {
        accA[m] += accB[m];
        accA[m] += __shfl_xor(accA[m], 16, 64);
        accA[m] += __shfl_xor(accA[m], 32, 64);
    }
    // quads 0/1 store the two float4 halves of this chunk (constant indices)
    if (quad < 2) {
        const float4 b4 = *(const float4*)(bias + i16 * 8 + quad * 4);
        float4 st;
        if (quad == 0) {
            st.x = accA[0] + b4.x; st.y = accA[1] + b4.y;
            st.z = accA[2] + b4.z; st.w = accA[3] + b4.w;
        } else {
            st.x = accA[4] + b4.x; st.y = accA[5] + b4.y;
            st.z = accA[6] + b4.z; st.w = accA[7] + b4.w;
        }
        *(float4*)(out + (size_t)n * HD + i16 * 8 + quad * 4) = st;
    }
}

// ---------------------------------------------------------------------------
// Kernel 4: alpha_pooled, edge order, fully coalesced; gathers from
// asrc/adst/rsumr (2.4 MB total, L2-resident).
// ---------------------------------------------------------------------------
static __device__ inline float apool1(
    int s, int d, const float* __restrict__ asrc,
    const float* __restrict__ adst, const float* __restrict__ rsumr)
{
    float4 a = *(const float4*)(asrc + s * 4);
    float4 b = *(const float4*)(adst + d * 4);
    float4 r = *(const float4*)(rsumr + d * 4);
    return 0.25f * (lrelu_exp(a.x + b.x) * r.x + lrelu_exp(a.y + b.y) * r.y +
                    lrelu_exp(a.z + b.z) * r.z + lrelu_exp(a.w + b.w) * r.w);
}

__global__ __launch_bounds__(256) void gat_apool(
    const int* __restrict__ ei, const float* __restrict__ asrc,
    const float* __restrict__ adst, const float* __restrict__ rsumr,
    float* __restrict__ apool)
{
    int e0 = (blockIdx.x * 256 + threadIdx.x) * 4;
    if (e0 >= NEDGES) return;
    int4 s = *(const int4*)(ei + e0);
    int4 d = *(const int4*)(ei + NEDGES + e0);
    float4 r;
    r.x = apool1(s.x, d.x, asrc, adst, rsumr);
    r.y = apool1(s.y, d.y, asrc, adst, rsumr);
    r.z = apool1(s.z, d.z, asrc, adst, rsumr);
    r.w = apool1(s.w, d.w, asrc, adst, rsumr);
    *(float4*)(apool + e0) = r;
}

// ---------------------------------------------------------------------------
extern "C" void kernel_launch(void* const* d_in, const int* in_sizes, int n_in,
                              void* d_out, int out_size, void* d_ws, size_t ws_size,
                              hipStream_t stream)
{
    const float* x       = (const float*)d_in[0];
    const int*   ei      = (const int*)d_in[1];
    const float* W       = (const float*)d_in[2];
    const float* att_src = (const float*)d_in[3];
    const float* att_dst = (const float*)d_in[4];
    const float* bias    = (const float*)d_in[5];

    float* out   = (float*)d_out;                    // (N,128)
    float* apool = out + (size_t)NNODES * HD;        // (E,)

    // workspace layout
    unsigned short* h = (unsigned short*)d_ws;            // N*128 bf16
    float* asrc  = (float*)(h + (size_t)NNODES * HD);     // N*4
    float* adst  = asrc + NNODES * 4;                     // N*4
    float* rsumr = adst + NNODES * 4;                     // N*4
    int*   Sg    = (int*)(rsumr + NNODES * 4);            // ABLK*257
    int*   coffB = Sg + ABLK * 257 + 4;                   // N
    int*   coffE = coffB + NNODES + 4;                    // N
    int*   sbuf  = coffE + NNODES + 4;                    // ABLK*2048
    unsigned short* csr = (unsigned short*)(sbuf + (size_t)ABLK * 2048); // NBINS*CAP

    gat_main<<<GEMMB + ABLK, 256, 0, stream>>>(
        x, W, att_src, att_dst, ei, h, asrc, adst, Sg, sbuf);
    gat_bin<<<NBINS, 1024, 0, stream>>>(Sg, sbuf, coffB, coffE, csr);
    gat_node<<<NNODES / 4, 256, 0, stream>>>(
        coffB, coffE, csr, asrc, adst, h, bias, out, rsumr);
    gat_apool<<<(NEDGES / 4 + 255) / 256, 256, 0, stream>>>(
        ei, asrc, adst, rsumr, apool);
}